// Round 6
// baseline (594.235 us; speedup 1.0000x reference)
//
#include <hip/hip_runtime.h>
#include <hip/hip_cooperative_groups.h>

namespace cg = cooperative_groups;

#define DIM 512
#define DIM2 1024
#define NGRAPH 512
#define LN_EPS 1e-5f
#define TPB 256
#define NSEG 8

typedef float f4 __attribute__((ext_vector_type(4)));

__device__ __forceinline__ f4 ntl(const f4* p) { return __builtin_nontemporal_load(p); }
__device__ __forceinline__ void nts(f4* p, f4 v) { __builtin_nontemporal_store(v, p); }

__device__ __forceinline__ void flush_acc(float* __restrict__ sums, int g, int c, f4 a) {
    if (g < 0) return;
    float* d = sums + (size_t)g * DIM + c * 4;
    atomicAdd(d + 0, a[0]);
    atomicAdd(d + 1, a[1]);
    atomicAdd(d + 2, a[2]);
    atomicAdd(d + 3, a[3]);
}

// ===========================================================================
// Cooperative fused kernel. Phases separated by grid.sync(). Grid size is
// determined at launch from the occupancy query; phases use gridDim.x.
// Requires gridDim.x >= 256 (guaranteed by host clamp).
// ===========================================================================
__global__ __launch_bounds__(TPB) void fused_kernel(
    const f4* __restrict__ x4, const int* __restrict__ bi,
    const float* __restrict__ W1, const float* __restrict__ b1,
    const float* __restrict__ W2, const float* __restrict__ b2,
    const float* __restrict__ gamma, const float* __restrict__ beta,
    float* __restrict__ sums, float* __restrict__ h1,
    f4* __restrict__ xnew4, float* __restrict__ hvn, int n_nodes)
{
    cg::grid_group grid = cg::this_grid();
    const int blk = blockIdx.x, t = threadIdx.x;
    const int nb = gridDim.x;

    __shared__ int sb9[9];
    __shared__ float sh_s[4][4], sh_ss[4][4];

    // ---------------- Phase 0: zero sums ----------------------------------
    for (int i = blk * TPB + t; i < NGRAPH * DIM; i += nb * TPB) sums[i] = 0.0f;
    grid.sync();

    // ---------------- Phase 1: segment sums (flush-on-graph-change) -------
    {
        const int rpb = (n_nodes + nb - 1) / nb;
        const int r0 = blk * rpb;
        const int r1 = min(n_nodes, r0 + rpb);
        const int par = t >> 7;      // 256 thr = 2 rows x 128 f4-cols
        const int c = t & 127;
        f4 acc = {0, 0, 0, 0};
        int curg = -1;
        int r = r0 + par;
        while (r + 6 < r1) {         // 4 independent row loads in flight
            f4 v0 = x4[(size_t)(r    ) * 128 + c];
            f4 v1 = x4[(size_t)(r + 2) * 128 + c];
            f4 v2 = x4[(size_t)(r + 4) * 128 + c];
            f4 v3 = x4[(size_t)(r + 6) * 128 + c];
            int g0 = bi[r], g1 = bi[r + 2], g2 = bi[r + 4], g3 = bi[r + 6];
            if (g0 != curg) { flush_acc(sums, curg, c, acc); acc = (f4){0,0,0,0}; curg = g0; }
            acc += v0;
            if (g1 != curg) { flush_acc(sums, curg, c, acc); acc = (f4){0,0,0,0}; curg = g1; }
            acc += v1;
            if (g2 != curg) { flush_acc(sums, curg, c, acc); acc = (f4){0,0,0,0}; curg = g2; }
            acc += v2;
            if (g3 != curg) { flush_acc(sums, curg, c, acc); acc = (f4){0,0,0,0}; curg = g3; }
            acc += v3;
            r += 8;
        }
        for (; r < r1; r += 2) {
            f4 v = x4[(size_t)r * 128 + c];
            int g = bi[r];
            if (g != curg) { flush_acc(sums, curg, c, acc); acc = (f4){0,0,0,0}; curg = g; }
            acc += v;
        }
        flush_acc(sums, curg, c, acc);
    }
    grid.sync();

    // ---------------- Phase 2: h1 = relu((sums/cnt) @ W1 + b1) ------------
    if (blk < 256) {
        const int col = (blk & 3) * 256 + t;
        const int r0 = (blk >> 2) * 8;
        if (t < 9) {
            int v = r0 + t;
            int lo = 0, hi = n_nodes;
            while (lo < hi) {
                int mid = (lo + hi) >> 1;
                if (bi[mid] < v) lo = mid + 1; else hi = mid;
            }
            sb9[t] = lo;
        }
        __syncthreads();
        float inv[8];
#pragma unroll
        for (int r = 0; r < 8; ++r) {
            int cnt = sb9[r + 1] - sb9[r];
            inv[r] = 1.0f / (float)(cnt > 0 ? cnt : 1);
        }
        float acc[8] = {0,0,0,0,0,0,0,0};
#pragma unroll 8
        for (int k = 0; k < DIM; ++k) {
            float w = W1[(size_t)k * DIM2 + col];
#pragma unroll
            for (int r = 0; r < 8; ++r)
                acc[r] += sums[(size_t)(r0 + r) * DIM + k] * w;
        }
        float bb = b1[col];
#pragma unroll
        for (int r = 0; r < 8; ++r) {
            float v = acc[r] * inv[r] + bb;
            h1[(size_t)(r0 + r) * DIM2 + col] = v > 0.0f ? v : 0.0f;
        }
    }
    grid.sync();

    // ---------------- Phase 3: hvn = LN(h1 @ W2 + b2) ---------------------
    if (blk < 128) {
        const int r0 = blk * 4;
        const int c0 = t, c1 = t + 256;
        float acc[4][2] = {{0,0},{0,0},{0,0},{0,0}};
#pragma unroll 8
        for (int k = 0; k < DIM2; ++k) {
            float w0 = W2[(size_t)k * DIM + c0];
            float w1 = W2[(size_t)k * DIM + c1];
#pragma unroll
            for (int r = 0; r < 4; ++r) {
                float a = h1[(size_t)(r0 + r) * DIM2 + k];
                acc[r][0] += a * w0;
                acc[r][1] += a * w1;
            }
        }
        float bb0 = b2[c0], bb1 = b2[c1];
        float v[4][2];
#pragma unroll
        for (int r = 0; r < 4; ++r) { v[r][0] = acc[r][0] + bb0; v[r][1] = acc[r][1] + bb1; }

        const int wid = t >> 6, lane = t & 63;
#pragma unroll
        for (int r = 0; r < 4; ++r) {
            float s = v[r][0] + v[r][1];
            float ss = v[r][0] * v[r][0] + v[r][1] * v[r][1];
#pragma unroll
            for (int off = 32; off > 0; off >>= 1) {
                s  += __shfl_xor(s,  off);
                ss += __shfl_xor(ss, off);
            }
            if (lane == 0) { sh_s[r][wid] = s; sh_ss[r][wid] = ss; }
        }
        __syncthreads();
        float gm0 = gamma[c0], gm1 = gamma[c1], bt0 = beta[c0], bt1 = beta[c1];
#pragma unroll
        for (int r = 0; r < 4; ++r) {
            float s = sh_s[r][0] + sh_s[r][1] + sh_s[r][2] + sh_s[r][3];
            float ss = sh_ss[r][0] + sh_ss[r][1] + sh_ss[r][2] + sh_ss[r][3];
            float mu  = s * (1.0f / DIM);
            float var = ss * (1.0f / DIM) - mu * mu;
            float rs  = rsqrtf(var + LN_EPS);
            hvn[(size_t)(r0 + r) * DIM + c0] = (v[r][0] - mu) * rs * gm0 + bt0;
            hvn[(size_t)(r0 + r) * DIM + c1] = (v[r][1] - mu) * rs * gm1 + bt1;
        }
    }
    grid.sync();

    // ---------------- Phase 4: x_new = x + hvn[bi], reverse chunks --------
    {
        const f4* hv4 = (const f4*)hvn;
        const int n4 = n_nodes * 128;
        const int chunk = (n4 + nb - 1) / nb;
        const int rb = (nb - 1) - blk;             // reverse: L3-hot tail first
        const int base = rb * chunk;
        const int end = min(n4, base + chunk);
        int j = base + t;
        for (; j + 3 * TPB < end; j += 4 * TPB) {
            const int i0 = j, i1 = j + TPB, i2 = j + 2 * TPB, i3 = j + 3 * TPB;
            f4 x0 = x4[i0], x1 = x4[i1], x2 = x4[i2], x3 = x4[i3];
            int g0 = bi[i0 >> 7], g1 = bi[i1 >> 7], g2 = bi[i2 >> 7], g3 = bi[i3 >> 7];
            f4 h0 = hv4[(g0 << 7) + (i0 & 127)];
            f4 h1v = hv4[(g1 << 7) + (i1 & 127)];
            f4 h2v = hv4[(g2 << 7) + (i2 & 127)];
            f4 h3v = hv4[(g3 << 7) + (i3 & 127)];
            nts(xnew4 + i0, x0 + h0);
            nts(xnew4 + i1, x1 + h1v);
            nts(xnew4 + i2, x2 + h2v);
            nts(xnew4 + i3, x3 + h3v);
        }
        for (; j < end; j += TPB) {
            f4 xv = x4[j];
            int g = bi[j >> 7];
            f4 hv = hv4[(g << 7) + (j & 127)];
            nts(xnew4 + j, xv + hv);
        }
    }
}

// ===========================================================================
// Fallback path (R4 structure, known-good) — used only if the cooperative
// launch is rejected by the runtime. Deterministic: same decision every call.
// ===========================================================================
__global__ __launch_bounds__(256) void zero_kernel(f4* __restrict__ p, int n4) {
    int i = blockIdx.x * 256 + threadIdx.x;
    const int stride = gridDim.x * 256;
    f4 z = {0.f, 0.f, 0.f, 0.f};
    for (; i < n4; i += stride) p[i] = z;
}

__global__ __launch_bounds__(128) void segsum_kernel(const f4* __restrict__ x4,
                                                     const int* __restrict__ bi,
                                                     float* __restrict__ sums,
                                                     int n_nodes) {
    const int g = blockIdx.x;
    __shared__ int sb[2];
    if (threadIdx.x < 2) {
        int v = g + (int)threadIdx.x;
        int lo = 0, hi = n_nodes;
        while (lo < hi) {
            int mid = (lo + hi) >> 1;
            if (bi[mid] < v) lo = mid + 1; else hi = mid;
        }
        sb[threadIdx.x] = lo;
    }
    __syncthreads();
    const int glo = sb[0], len = sb[1] - sb[0];
    const int s = blockIdx.y;
    const int r0 = glo + (len * s) / NSEG;
    const int r1 = glo + (len * (s + 1)) / NSEG;
    const int t = threadIdx.x;

    f4 a0 = {0,0,0,0}, a1 = {0,0,0,0}, a2 = {0,0,0,0}, a3 = {0,0,0,0};
    int r = r0;
    for (; r + 4 <= r1; r += 4) {
        a0 += x4[(size_t)(r + 0) * 128 + t];
        a1 += x4[(size_t)(r + 1) * 128 + t];
        a2 += x4[(size_t)(r + 2) * 128 + t];
        a3 += x4[(size_t)(r + 3) * 128 + t];
    }
    for (; r < r1; ++r) a0 += x4[(size_t)r * 128 + t];
    a0 += a1 + a2 + a3;
    flush_acc(sums, g, t, a0);
}

__global__ __launch_bounds__(256) void gemm1_kernel(const float* __restrict__ S,
                                                    const int* __restrict__ bi,
                                                    const float* __restrict__ W1,
                                                    const float* __restrict__ b1,
                                                    float* __restrict__ h1,
                                                    int n_nodes) {
    const int col = blockIdx.x * 256 + threadIdx.x;
    const int r0 = blockIdx.y * 8;
    __shared__ int sb[9];
    if (threadIdx.x < 9) {
        int v = r0 + (int)threadIdx.x;
        int lo = 0, hi = n_nodes;
        while (lo < hi) {
            int mid = (lo + hi) >> 1;
            if (bi[mid] < v) lo = mid + 1; else hi = mid;
        }
        sb[threadIdx.x] = lo;
    }
    __syncthreads();
    float inv[8];
#pragma unroll
    for (int r = 0; r < 8; ++r) {
        int c = sb[r + 1] - sb[r];
        inv[r] = 1.0f / (float)(c > 0 ? c : 1);
    }
    float acc[8] = {0,0,0,0,0,0,0,0};
#pragma unroll 8
    for (int k = 0; k < DIM; ++k) {
        float w = W1[(size_t)k * DIM2 + col];
#pragma unroll
        for (int r = 0; r < 8; ++r)
            acc[r] += S[(size_t)(r0 + r) * DIM + k] * w;
    }
    float bb = b1[col];
#pragma unroll
    for (int r = 0; r < 8; ++r) {
        float v = acc[r] * inv[r] + bb;
        h1[(size_t)(r0 + r) * DIM2 + col] = v > 0.0f ? v : 0.0f;
    }
}

__global__ __launch_bounds__(512) void ffn2_ln_kernel(const float* __restrict__ h1,
                                                      const float* __restrict__ W2,
                                                      const float* __restrict__ b2,
                                                      const float* __restrict__ gamma,
                                                      const float* __restrict__ beta,
                                                      float* __restrict__ out) {
    const int col = threadIdx.x;
    const int r0 = blockIdx.x * 8;
    float acc[8] = {0,0,0,0,0,0,0,0};
#pragma unroll 8
    for (int k = 0; k < DIM2; ++k) {
        float w = W2[(size_t)k * DIM + col];
#pragma unroll
        for (int r = 0; r < 8; ++r)
            acc[r] += h1[(size_t)(r0 + r) * DIM2 + k] * w;
    }
    float bb = b2[col];
    float v[8];
#pragma unroll
    for (int r = 0; r < 8; ++r) v[r] = acc[r] + bb;

    __shared__ float sh_s[8][8], sh_ss[8][8];
    const int wid = threadIdx.x >> 6, lane = threadIdx.x & 63;
#pragma unroll
    for (int r = 0; r < 8; ++r) {
        float s = v[r], ss = v[r] * v[r];
#pragma unroll
        for (int off = 32; off > 0; off >>= 1) {
            s  += __shfl_xor(s,  off);
            ss += __shfl_xor(ss, off);
        }
        if (lane == 0) { sh_s[r][wid] = s; sh_ss[r][wid] = ss; }
    }
    __syncthreads();
    float gm = gamma[col], bt = beta[col];
#pragma unroll
    for (int r = 0; r < 8; ++r) {
        float s = 0.f, ss = 0.f;
#pragma unroll
        for (int w = 0; w < 8; ++w) { s += sh_s[r][w]; ss += sh_ss[r][w]; }
        float mu  = s * (1.0f / DIM);
        float var = ss * (1.0f / DIM) - mu * mu;
        float rs  = rsqrtf(var + LN_EPS);
        out[(size_t)(r0 + r) * DIM + col] = (v[r] - mu) * rs * gm + bt;
    }
}

__global__ __launch_bounds__(256) void resid_kernel(const f4* __restrict__ x4,
                                                    const int* __restrict__ bi,
                                                    const f4* __restrict__ hv4,
                                                    f4* __restrict__ out4,
                                                    int n4) {
    const int S = gridDim.x * 256;
    int i = blockIdx.x * 256 + threadIdx.x;
    for (; i + 3 * S < n4; i += 4 * S) {
        const int i0 = i, i1 = i + S, i2 = i + 2 * S, i3 = i + 3 * S;
        f4 x0 = ntl(x4 + i0), x1 = ntl(x4 + i1), x2 = ntl(x4 + i2), x3 = ntl(x4 + i3);
        int g0 = bi[i0 >> 7], g1 = bi[i1 >> 7], g2 = bi[i2 >> 7], g3 = bi[i3 >> 7];
        f4 h0 = hv4[(g0 << 7) + (i0 & 127)];
        f4 h1v = hv4[(g1 << 7) + (i1 & 127)];
        f4 h2v = hv4[(g2 << 7) + (i2 & 127)];
        f4 h3v = hv4[(g3 << 7) + (i3 & 127)];
        nts(out4 + i0, x0 + h0);
        nts(out4 + i1, x1 + h1v);
        nts(out4 + i2, x2 + h2v);
        nts(out4 + i3, x3 + h3v);
    }
    for (; i < n4; i += S) {
        f4 xv = ntl(x4 + i);
        int g = bi[i >> 7];
        f4 hv = hv4[(g << 7) + (i & 127)];
        nts(out4 + i, xv + hv);
    }
}

extern "C" void kernel_launch(void* const* d_in, const int* in_sizes, int n_in,
                              void* d_out, int out_size, void* d_ws, size_t ws_size,
                              hipStream_t stream) {
    const f4*    x4    = (const f4*)d_in[0];
    const int*   bidx  = (const int*)d_in[1];   // int32 per harness contract
    const float* W1    = (const float*)d_in[2];
    const float* b1    = (const float*)d_in[3];
    const float* W2    = (const float*)d_in[4];
    const float* b2    = (const float*)d_in[5];
    const float* gamma = (const float*)d_in[6];
    const float* beta  = (const float*)d_in[7];

    int n_nodes = in_sizes[1];
    const size_t x_elems = (size_t)n_nodes * DIM;

    float* out   = (float*)d_out;
    f4*    xnew4 = (f4*)out;                  // output 0: [n_nodes, 512]
    float* hvn   = out + x_elems;             // output 1: [512, 512]

    float* sums = (float*)d_ws;               // 512*512 atomic accumulator
    float* h1   = sums + (size_t)NGRAPH * DIM;

    // Occupancy-clamped cooperative grid (deterministic query).
    int maxPerCU = 0;
    hipError_t qe = hipOccupancyMaxActiveBlocksPerMultiprocessor(
        &maxPerCU, (const void*)fused_kernel, TPB, 0);
    int nblk = 1024;
    if (qe == hipSuccess && maxPerCU >= 1) {
        int cap = maxPerCU * 256;             // 256 CUs
        if (cap < nblk) nblk = cap;
    }
    if (nblk < 256) nblk = 256;               // phases 2/3 need >=256 blocks

    void* args[] = {
        (void*)&x4, (void*)&bidx, (void*)&W1, (void*)&b1, (void*)&W2,
        (void*)&b2, (void*)&gamma, (void*)&beta, (void*)&sums, (void*)&h1,
        (void*)&xnew4, (void*)&hvn, (void*)&n_nodes
    };
    hipError_t le = hipLaunchCooperativeKernel((void*)fused_kernel, dim3(nblk),
                                               dim3(TPB), args, 0, stream);
    if (le != hipSuccess) {
        // Deterministic fallback: known-good multi-kernel path.
        zero_kernel<<<128, 256, 0, stream>>>((f4*)sums, NGRAPH * DIM / 4);
        segsum_kernel<<<dim3(NGRAPH, NSEG), 128, 0, stream>>>(x4, bidx, sums, n_nodes);
        gemm1_kernel<<<dim3(4, 64), 256, 0, stream>>>(sums, bidx, W1, b1, h1, n_nodes);
        ffn2_ln_kernel<<<64, 512, 0, stream>>>(h1, W2, b2, gamma, beta, hvn);
        const int n4 = (int)(x_elems / 4);
        resid_kernel<<<4096, 256, 0, stream>>>(x4, bidx, (const f4*)hvn, xnew4, n4);
    }
}

// Round 7
// 392.114 us; speedup vs baseline: 1.5155x; 1.5155x over previous
//
#include <hip/hip_runtime.h>

#define DIM 512
#define DIM2 1024
#define NGRAPH 512
#define LN_EPS 1e-5f
#define TPB 256
#define NB 2048   // chunk count for K1/K4 — must match for the L3-reuse trick

typedef float f4 __attribute__((ext_vector_type(4)));

__device__ __forceinline__ void nts(f4* p, f4 v) { __builtin_nontemporal_store(v, p); }

// ---------------------------------------------------------------------------
// K0: zero the atomic accumulation buffer (1 MB; re-runs every replay).
// ---------------------------------------------------------------------------
__global__ __launch_bounds__(256) void zero_kernel(f4* __restrict__ p, int n4) {
    int i = blockIdx.x * 256 + threadIdx.x;
    const int stride = gridDim.x * 256;
    f4 z = {0.f, 0.f, 0.f, 0.f};
    for (; i < n4; i += stride) p[i] = z;
}

// ---------------------------------------------------------------------------
// K1: segment sums, chunk-contiguous. 2048 blocks x 256 thr (32 waves/CU).
// Each block owns rows [blk*rpb, blk*rpb+rpb). Graph runs inside the chunk
// are found by uniform binary search (sorted batch_idx), then summed with a
// BRANCHLESS 16-row inner loop: 8 independent 16B loads in flight per lane
// (2 rows x 128 f4-cols thread layout). One atomic flush per run.
// Cached (non-NT) reads: deliberately leaves x hot in L3 for K4.
// ---------------------------------------------------------------------------
__global__ __launch_bounds__(TPB) void segsum_kernel(const f4* __restrict__ x4,
                                                     const int* __restrict__ bi,
                                                     float* __restrict__ sums,
                                                     int n_nodes, int rpb) {
    const int blk = blockIdx.x, t = threadIdx.x;
    const int r0 = blk * rpb;
    const int r1 = min(n_nodes, r0 + rpb);
    if (r0 >= r1) return;
    const int par = t >> 7;      // row parity: 256 thr = 2 rows x 128 f4-cols
    const int c = t & 127;

    int cur = r0;
    while (cur < r1) {
        const int g = bi[cur];
        // end of this graph's run inside [cur, r1)
        int lo = cur + 1, hi = r1;
        while (lo < hi) {
            int mid = (lo + hi) >> 1;
            if (bi[mid] <= g) lo = mid + 1; else hi = mid;
        }
        const int send = lo;

        f4 a0={0,0,0,0}, a1={0,0,0,0}, a2={0,0,0,0}, a3={0,0,0,0};
        f4 a4={0,0,0,0}, a5={0,0,0,0}, a6={0,0,0,0}, a7={0,0,0,0};
        int r = cur;
        for (; r + 16 <= send; r += 16) {            // branchless, 8 loads in flight
            const size_t b = (size_t)(r + par) * 128 + c;
            f4 v0 = x4[b];        f4 v1 = x4[b + 256];
            f4 v2 = x4[b + 512];  f4 v3 = x4[b + 768];
            f4 v4 = x4[b + 1024]; f4 v5 = x4[b + 1280];
            f4 v6 = x4[b + 1536]; f4 v7 = x4[b + 1792];
            a0 += v0; a1 += v1; a2 += v2; a3 += v3;
            a4 += v4; a5 += v5; a6 += v6; a7 += v7;
        }
        for (int rr = r + par; rr < send; rr += 2)   // tail (predicated, short)
            a0 += x4[(size_t)rr * 128 + c];

        a0 += a1 + a2 + a3 + a4 + a5 + a6 + a7;
        float* d = sums + (size_t)g * DIM + c * 4;   // both parities hit same d
        atomicAdd(d + 0, a0[0]);
        atomicAdd(d + 1, a0[1]);
        atomicAdd(d + 2, a0[2]);
        atomicAdd(d + 3, a0[3]);
        cur = send;
    }
}

// ---------------------------------------------------------------------------
// K2: h1 = relu((sums * 1/cnt) @ W1 + b1); mean fold after the K-loop.
// grid = (4 col-blocks of 256, 64 row-blocks of 8).
// ---------------------------------------------------------------------------
__global__ __launch_bounds__(256) void gemm1_kernel(const float* __restrict__ S,
                                                    const int* __restrict__ bi,
                                                    const float* __restrict__ W1,
                                                    const float* __restrict__ b1,
                                                    float* __restrict__ h1,
                                                    int n_nodes) {
    const int col = blockIdx.x * 256 + threadIdx.x;
    const int r0 = blockIdx.y * 8;
    __shared__ int sb[9];
    if (threadIdx.x < 9) {
        int v = r0 + (int)threadIdx.x;
        int lo = 0, hi = n_nodes;
        while (lo < hi) {
            int mid = (lo + hi) >> 1;
            if (bi[mid] < v) lo = mid + 1; else hi = mid;
        }
        sb[threadIdx.x] = lo;
    }
    __syncthreads();
    float inv[8];
#pragma unroll
    for (int r = 0; r < 8; ++r) {
        int cnt = sb[r + 1] - sb[r];
        inv[r] = 1.0f / (float)(cnt > 0 ? cnt : 1);
    }
    float acc[8] = {0,0,0,0,0,0,0,0};
#pragma unroll 8
    for (int k = 0; k < DIM; ++k) {
        float w = W1[(size_t)k * DIM2 + col];
#pragma unroll
        for (int r = 0; r < 8; ++r)
            acc[r] += S[(size_t)(r0 + r) * DIM + k] * w;
    }
    float bb = b1[col];
#pragma unroll
    for (int r = 0; r < 8; ++r) {
        float v = acc[r] * inv[r] + bb;
        h1[(size_t)(r0 + r) * DIM2 + col] = v > 0.0f ? v : 0.0f;
    }
}

// ---------------------------------------------------------------------------
// K3: fused h2 = h1 @ W2 + b2 then LayerNorm -> hvn (d_out tail).
// 64 blocks x 512 thr (8 rows x 512 cols per block).
// ---------------------------------------------------------------------------
__global__ __launch_bounds__(512) void ffn2_ln_kernel(const float* __restrict__ h1,
                                                      const float* __restrict__ W2,
                                                      const float* __restrict__ b2,
                                                      const float* __restrict__ gamma,
                                                      const float* __restrict__ beta,
                                                      float* __restrict__ out) {
    const int col = threadIdx.x;
    const int r0 = blockIdx.x * 8;
    float acc[8] = {0,0,0,0,0,0,0,0};
#pragma unroll 8
    for (int k = 0; k < DIM2; ++k) {
        float w = W2[(size_t)k * DIM + col];
#pragma unroll
        for (int r = 0; r < 8; ++r)
            acc[r] += h1[(size_t)(r0 + r) * DIM2 + k] * w;
    }
    float bb = b2[col];
    float v[8];
#pragma unroll
    for (int r = 0; r < 8; ++r) v[r] = acc[r] + bb;

    __shared__ float sh_s[8][8], sh_ss[8][8];
    const int wid = threadIdx.x >> 6, lane = threadIdx.x & 63;
#pragma unroll
    for (int r = 0; r < 8; ++r) {
        float s = v[r], ss = v[r] * v[r];
#pragma unroll
        for (int off = 32; off > 0; off >>= 1) {
            s  += __shfl_xor(s,  off);
            ss += __shfl_xor(ss, off);
        }
        if (lane == 0) { sh_s[r][wid] = s; sh_ss[r][wid] = ss; }
    }
    __syncthreads();
    float gm = gamma[col], bt = beta[col];
#pragma unroll
    for (int r = 0; r < 8; ++r) {
        float s = 0.f, ss = 0.f;
#pragma unroll
        for (int w = 0; w < 8; ++w) { s += sh_s[r][w]; ss += sh_ss[r][w]; }
        float mu  = s * (1.0f / DIM);
        float var = ss * (1.0f / DIM) - mu * mu;
        float rs  = rsqrtf(var + LN_EPS);
        out[(size_t)(r0 + r) * DIM + col] = (v[r] - mu) * rs * gm + bt;
    }
}

// ---------------------------------------------------------------------------
// K4: x_new = x + hvn[batch_idx]. Same 2048-chunk partition as K1; each
// block walks its chunk's groups TAIL-FIRST (most-recently-cached x lines
// first -> L3 hits before LRU eviction). Cached x loads, NT stores.
// 8 positions per thread per group = 8 independent loads in flight.
// ---------------------------------------------------------------------------
__global__ __launch_bounds__(TPB) void resid_kernel(const f4* __restrict__ x4,
                                                    const int* __restrict__ bi,
                                                    const f4* __restrict__ hv4,
                                                    f4* __restrict__ out4,
                                                    int n_nodes, int rpb) {
    const int blk = blockIdx.x, t = threadIdx.x;
    const int r0 = blk * rpb;
    const int r1 = min(n_nodes, r0 + rpb);
    if (r0 >= r1) return;
    const int base = r0 * 128, endi = r1 * 128;   // f4 index range
    const int gsz = TPB * 8;
    const int ngrp = (endi - base + gsz - 1) / gsz;

    for (int gi = ngrp - 1; gi >= 0; --gi) {      // reverse macro-order
        const int gb = base + gi * gsz;
        if (gb + gsz <= endi) {
            const int j = gb + t;
            f4 xv[8]; int rw[8]; f4 hv[8];
#pragma unroll
            for (int k = 0; k < 8; ++k) xv[k] = x4[j + k * TPB];
#pragma unroll
            for (int k = 0; k < 8; ++k) rw[k] = bi[(j + k * TPB) >> 7];
#pragma unroll
            for (int k = 0; k < 8; ++k) hv[k] = hv4[(rw[k] << 7) + ((j + k * TPB) & 127)];
#pragma unroll
            for (int k = 0; k < 8; ++k) nts(out4 + j + k * TPB, xv[k] + hv[k]);
        } else {
            for (int j = gb + t; j < endi; j += TPB) {
                f4 xv = x4[j];
                int g = bi[j >> 7];
                nts(out4 + j, xv + hv4[(g << 7) + (j & 127)]);
            }
        }
    }
}

extern "C" void kernel_launch(void* const* d_in, const int* in_sizes, int n_in,
                              void* d_out, int out_size, void* d_ws, size_t ws_size,
                              hipStream_t stream) {
    const f4*    x4    = (const f4*)d_in[0];
    const int*   bidx  = (const int*)d_in[1];   // int32 per harness contract
    const float* W1    = (const float*)d_in[2];
    const float* b1    = (const float*)d_in[3];
    const float* W2    = (const float*)d_in[4];
    const float* b2    = (const float*)d_in[5];
    const float* gamma = (const float*)d_in[6];
    const float* beta  = (const float*)d_in[7];

    const int n_nodes = in_sizes[1];
    const size_t x_elems = (size_t)n_nodes * DIM;

    float* out   = (float*)d_out;
    f4*    xnew4 = (f4*)out;                  // output 0: [n_nodes, 512]
    float* hvn   = out + x_elems;             // output 1: [512, 512]

    float* sums = (float*)d_ws;               // 512*512 atomic accumulator
    float* h1   = sums + (size_t)NGRAPH * DIM;

    const int rpb = (n_nodes + NB - 1) / NB;  // rows per chunk (K1 == K4)

    zero_kernel<<<128, 256, 0, stream>>>((f4*)sums, NGRAPH * DIM / 4);
    segsum_kernel<<<NB, TPB, 0, stream>>>(x4, bidx, sums, n_nodes, rpb);
    gemm1_kernel<<<dim3(4, 64), 256, 0, stream>>>(sums, bidx, W1, b1, h1, n_nodes);
    ffn2_ln_kernel<<<64, 512, 0, stream>>>(h1, W2, b2, gamma, beta, hvn);
    resid_kernel<<<NB, TPB, 0, stream>>>(x4, bidx, (const f4*)hvn, xnew4,
                                         n_nodes, rpb);
}